// Round 3
// baseline (1129.614 us; speedup 1.0000x reference)
//
#include <hip/hip_runtime.h>
#include <cstdint>
#include <cstddef>

// Problem constants
#define BB 4096
#define DD 2048
#define NHH 16
#define NTT 4
#define DKK 128

using u16 = unsigned short;
using u32 = unsigned int;

typedef __bf16 bf16x8 __attribute__((ext_vector_type(8)));
typedef float f32x4 __attribute__((ext_vector_type(4)));

__device__ __forceinline__ float b2f(u16 u) {
    union { float f; u32 i; } c; c.i = ((u32)u) << 16; return c.f;
}
__device__ __forceinline__ u16 f2b(float f) {
    union { float f; u32 i; } c; c.f = f;
    u32 x = c.i;
    u32 r = (x + 0x7fffu + ((x >> 16) & 1u)) >> 16;  // RNE
    return (u16)r;
}
// pack two f32 -> two bf16 (round-half-up via +0x8000, then v_perm byte select)
__device__ __forceinline__ u32 pk(float lo, float hi) {
    u32 a = __builtin_bit_cast(u32, lo) + 0x8000u;
    u32 b = __builtin_bit_cast(u32, hi) + 0x8000u;
    return __builtin_amdgcn_perm(b, a, 0x07060302u);  // {b[31:16], a[31:16]}
}

__device__ __forceinline__ void load_lds16(const void* g, void* l) {
    __builtin_amdgcn_global_load_lds((const __attribute__((address_space(1))) void*)g,
                                     (__attribute__((address_space(3))) void*)l,
                                     16, 0, 0);
}

// ---------------------------------------------------------------------------
// Kernel 0: f32 -> bf16 conversion (RNE), 8 elements/thread. n must be mult of 8.
// ---------------------------------------------------------------------------
__global__ __launch_bounds__(256) void cvt_kernel(const float* __restrict__ src,
                                                  u16* __restrict__ dst, int n)
{
    const int i = (blockIdx.x * 256 + threadIdx.x) * 8;
    if (i + 7 >= n) {
        for (int j = i; j < n; ++j) dst[j] = f2b(src[j]);
        return;
    }
    float4 a = *(const float4*)(src + i);
    float4 b = *(const float4*)(src + i + 4);
    *(uint4*)(dst + i) = make_uint4(pk(a.x, a.y), pk(a.z, a.w),
                                    pk(b.x, b.y), pk(b.z, b.w));
}

// ---------------------------------------------------------------------------
// Kernel 1: one projection GEMM.  C[m][n] = sum_k A[m][k]*W[n][k] + bias[n]
// A row m=(b*4+t) -> e_t[b][:] (f32, converted in-register to bf16).
// B = Wbuf bf16 via global_load_lds(16B).  128x128 tile, BK=32, 16x16x32 MFMA.
// ---------------------------------------------------------------------------
__global__ __launch_bounds__(256) void qkv_gemm(
    const float* __restrict__ e0, const float* __restrict__ e1,
    const float* __restrict__ e2, const float* __restrict__ e3,
    const u16* __restrict__ W, const float* __restrict__ bia,
    u16* __restrict__ C)
{
    __shared__ __align__(16) u16 As[128 * 32];
    __shared__ __align__(16) u16 Bs[128 * 32];

    const int tid = threadIdx.x;
    const int m0 = blockIdx.x * 128;
    const int n0 = blockIdx.y * 128;

    // A staging: thread covers LDS row ra = tid>>1, k-half ka = (tid&1)*16
    const int ra = tid >> 1;
    const int ka = (tid & 1) * 16;
    const int ma = m0 + ra;
    const int ta = ma & 3;
    const float* ea = (ta == 0) ? e0 : (ta == 1) ? e1 : (ta == 2) ? e2 : e3;
    const float* srcA = ea + (size_t)(ma >> 2) * DD + ka;
    uint4* ldsA = (uint4*)((char*)As + ra * 64 + ka * 2);

    // B staging via global_load_lds: row rb = tid>>2 (+64 for chunk 2)
    const int rb = tid >> 2;
    const int kb = (tid & 3) * 8;
    const u16* srcB1 = W + (size_t)(n0 + rb) * DD + kb;
    const u16* srcB2 = srcB1 + (size_t)64 * DD;
    const int wave = tid >> 6;
    char* ldsB1 = (char*)Bs + wave * 1024;
    char* ldsB2 = (char*)Bs + 4096 + wave * 1024;

    const int lane = tid & 63;
    const int wm = (wave >> 1) * 64;
    const int wn = (wave & 1) * 64;
    const int lrow = lane & 15;
    const int lk = (lane >> 4) * 8;

    f32x4 acc[4][4] = {};

    // prologue A loads (16 f32)
    float4 a0 = *(const float4*)(srcA);
    float4 a1 = *(const float4*)(srcA + 4);
    float4 a2 = *(const float4*)(srcA + 8);
    float4 a3 = *(const float4*)(srcA + 12);

    for (int k0 = 0; k0 < DD; k0 += 32) {
        __syncthreads();   // prior iteration's fragment reads complete
        uint4 q0, q1;
        q0.x = pk(a0.x, a0.y); q0.y = pk(a0.z, a0.w);
        q0.z = pk(a1.x, a1.y); q0.w = pk(a1.z, a1.w);
        q1.x = pk(a2.x, a2.y); q1.y = pk(a2.z, a2.w);
        q1.z = pk(a3.x, a3.y); q1.w = pk(a3.z, a3.w);
        ldsA[0] = q0;
        ldsA[1] = q1;
        load_lds16(srcB1, ldsB1);
        load_lds16(srcB2, ldsB2);
        srcB1 += 32; srcB2 += 32;
        __syncthreads();   // staging visible (vmcnt+lgkmcnt drained by barrier)

        // prefetch next A tile into registers; MFMA below hides the latency
        if (k0 + 32 < DD) {
            srcA += 32;
            a0 = *(const float4*)(srcA);
            a1 = *(const float4*)(srcA + 4);
            a2 = *(const float4*)(srcA + 8);
            a3 = *(const float4*)(srcA + 12);
        }

        bf16x8 af[4], bfr[4];
#pragma unroll
        for (int i = 0; i < 4; ++i)
            af[i] = *(const bf16x8*)(As + (wm + i * 16 + lrow) * 32 + lk);
#pragma unroll
        for (int i = 0; i < 4; ++i)
            bfr[i] = *(const bf16x8*)(Bs + (wn + i * 16 + lrow) * 32 + lk);
#pragma unroll
        for (int mi = 0; mi < 4; ++mi)
#pragma unroll
            for (int ni = 0; ni < 4; ++ni)
                acc[mi][ni] = __builtin_amdgcn_mfma_f32_16x16x32_bf16(af[mi], bfr[ni], acc[mi][ni], 0, 0, 0);
    }

    // epilogue: C/D layout col=lane&15, row=(lane>>4)*4+reg  [m89-verified]
#pragma unroll
    for (int mi = 0; mi < 4; ++mi) {
#pragma unroll
        for (int r = 0; r < 4; ++r) {
            const int grow = m0 + wm + mi * 16 + (lane >> 4) * 4 + r;
#pragma unroll
            for (int ni = 0; ni < 4; ++ni) {
                const int gcol = n0 + wn + ni * 16 + (lane & 15);
                C[(size_t)grow * DD + gcol] = f2b(acc[mi][ni][r] + bia[gcol]);
            }
        }
    }
}

// ---------------------------------------------------------------------------
// Kernel 2: attention per (b,h), one wave each.  Softmax over 4 keys with
// quality gating; token-mean folded into key weights.  ctx is written STRIDED
// into QC row 4b (race-free: wave (b,h) owns rows 4b..4b+3 x its col slice).
// ---------------------------------------------------------------------------
__global__ __launch_bounds__(256) void attn_kernel(
    u16* QC,                                   // Q buffer, NOT restrict (read+write)
    const u16* __restrict__ K, const u16* __restrict__ V,
    const float* __restrict__ qual)
{
    const int tid = threadIdx.x;
    const int lane = tid & 63;
    const int wid = tid >> 6;
    const int p = blockIdx.x * 4 + wid;        // 0..65535
    const int b = p >> 4;
    const int h = p & 15;
    const int col = h * 128 + lane * 2;

    float2 q[4], k[4], v[4];
#pragma unroll
    for (int t = 0; t < 4; ++t) {
        const size_t off = (size_t)(b * 4 + t) * DD + col;
        u32 uq = *(const u32*)(QC + off);
        u32 uk = *(const u32*)(K + off);
        u32 uv = *(const u32*)(V + off);
        q[t] = make_float2(b2f((u16)uq), b2f((u16)(uq >> 16)));
        k[t] = make_float2(b2f((u16)uk), b2f((u16)(uk >> 16)));
        v[t] = make_float2(b2f((u16)uv), b2f((u16)(uv >> 16)));
    }

    float s[4][4];
#pragma unroll
    for (int t = 0; t < 4; ++t)
#pragma unroll
        for (int j = 0; j < 4; ++j)
            s[t][j] = q[t].x * k[j].x + q[t].y * k[j].y;

#pragma unroll
    for (int off = 32; off >= 1; off >>= 1)
#pragma unroll
        for (int t = 0; t < 4; ++t)
#pragma unroll
            for (int j = 0; j < 4; ++j)
                s[t][j] += __shfl_xor(s[t][j], off);

    const float scale = 0.08838834764831845f;   // 1/sqrt(128)
    float qj[4];
#pragma unroll
    for (int j = 0; j < 4; ++j) qj[j] = qual[b * 4 + j] * scale;

    float wsum[4] = {0.f, 0.f, 0.f, 0.f};
#pragma unroll
    for (int t = 0; t < 4; ++t) {
        float sm[4]; float mx = -1e30f;
#pragma unroll
        for (int j = 0; j < 4; ++j) { sm[j] = s[t][j] * qj[j]; mx = fmaxf(mx, sm[j]); }
        float ex[4]; float se = 0.f;
#pragma unroll
        for (int j = 0; j < 4; ++j) { ex[j] = __expf(sm[j] - mx); se += ex[j]; }
        float inv = 1.0f / se;
#pragma unroll
        for (int j = 0; j < 4; ++j) wsum[j] += ex[j] * inv;
    }

    float cx = 0.f, cy = 0.f;
#pragma unroll
    for (int j = 0; j < 4; ++j) { cx += wsum[j] * v[j].x; cy += wsum[j] * v[j].y; }
    cx *= 0.25f; cy *= 0.25f;

    // strided ctx write: row 4b of QC (after all QC reads above)
    *(u32*)(QC + (size_t)(b * 4) * DD + col) = (u32)f2b(cx) | ((u32)f2b(cy) << 16);
}

// ---------------------------------------------------------------------------
// Kernel 3: O-projection.  A = ctx strided (row m at QC + 4m*DD), B = Wbuf.
// Y (f32) = A @ Wo^T + bo.
// ---------------------------------------------------------------------------
__global__ __launch_bounds__(256) void o_gemm(
    const u16* __restrict__ A, const u16* __restrict__ W,
    const float* __restrict__ bia, float* __restrict__ Y)
{
    __shared__ __align__(16) u16 As[128 * 32];
    __shared__ __align__(16) u16 Bs[128 * 32];

    const int tid = threadIdx.x;
    const int m0 = blockIdx.x * 128;
    const int n0 = blockIdx.y * 128;

    const int rb = tid >> 2;
    const int kb = (tid & 3) * 8;
    const u16* srcA1 = A + (size_t)(4 * (m0 + rb)) * DD + kb;   // strided rows
    const u16* srcA2 = srcA1 + (size_t)(4 * 64) * DD;
    const u16* srcB1 = W + (size_t)(n0 + rb) * DD + kb;
    const u16* srcB2 = srcB1 + (size_t)64 * DD;

    const int wave = tid >> 6;
    char* ldsA1 = (char*)As + wave * 1024;
    char* ldsA2 = (char*)As + 4096 + wave * 1024;
    char* ldsB1 = (char*)Bs + wave * 1024;
    char* ldsB2 = (char*)Bs + 4096 + wave * 1024;

    const int lane = tid & 63;
    const int wm = (wave >> 1) * 64;
    const int wn = (wave & 1) * 64;
    const int lrow = lane & 15;
    const int lk = (lane >> 4) * 8;

    f32x4 acc[4][4] = {};

    for (int k0 = 0; k0 < DD; k0 += 32) {
        __syncthreads();
        load_lds16(srcA1, ldsA1);
        load_lds16(srcA2, ldsA2);
        load_lds16(srcB1, ldsB1);
        load_lds16(srcB2, ldsB2);
        srcA1 += 32; srcA2 += 32; srcB1 += 32; srcB2 += 32;
        __syncthreads();

        bf16x8 af[4], bfr[4];
#pragma unroll
        for (int i = 0; i < 4; ++i)
            af[i] = *(const bf16x8*)(As + (wm + i * 16 + lrow) * 32 + lk);
#pragma unroll
        for (int i = 0; i < 4; ++i)
            bfr[i] = *(const bf16x8*)(Bs + (wn + i * 16 + lrow) * 32 + lk);
#pragma unroll
        for (int mi = 0; mi < 4; ++mi)
#pragma unroll
            for (int ni = 0; ni < 4; ++ni)
                acc[mi][ni] = __builtin_amdgcn_mfma_f32_16x16x32_bf16(af[mi], bfr[ni], acc[mi][ni], 0, 0, 0);
    }

#pragma unroll
    for (int mi = 0; mi < 4; ++mi) {
#pragma unroll
        for (int r = 0; r < 4; ++r) {
            const int grow = m0 + wm + mi * 16 + (lane >> 4) * 4 + r;
#pragma unroll
            for (int ni = 0; ni < 4; ++ni) {
                const int gcol = n0 + wn + ni * 16 + (lane & 15);
                Y[(size_t)grow * DD + gcol] = acc[mi][ni][r] + bia[gcol];
            }
        }
    }
}

// ---------------------------------------------------------------------------
// Kernel 4: residual mean + LayerNorm.  One block per row; all f32 I/O.
// ---------------------------------------------------------------------------
__global__ __launch_bounds__(256) void ln_kernel(
    const float* __restrict__ Y,
    const float* __restrict__ e0, const float* __restrict__ e1,
    const float* __restrict__ e2, const float* __restrict__ e3,
    const float* __restrict__ gamma, const float* __restrict__ beta,
    float* __restrict__ out)
{
    const int r = blockIdx.x;
    const int tid = threadIdx.x;
    const int c = tid * 8;
    const size_t base = (size_t)r * DD + c;

    float v[8];
    {
        float4 y0 = *(const float4*)(Y + base);
        float4 y1 = *(const float4*)(Y + base + 4);
        float a[8] = {0, 0, 0, 0, 0, 0, 0, 0};
        const float* eps[4] = {e0, e1, e2, e3};
#pragma unroll
        for (int q = 0; q < 4; ++q) {
            float4 p0 = *(const float4*)(eps[q] + base);
            float4 p1 = *(const float4*)(eps[q] + base + 4);
            a[0] += p0.x; a[1] += p0.y; a[2] += p0.z; a[3] += p0.w;
            a[4] += p1.x; a[5] += p1.y; a[6] += p1.z; a[7] += p1.w;
        }
        float yv[8] = {y0.x, y0.y, y0.z, y0.w, y1.x, y1.y, y1.z, y1.w};
#pragma unroll
        for (int i = 0; i < 8; ++i) v[i] = yv[i] + 0.25f * a[i];
    }

    float s = 0.f, sq = 0.f;
#pragma unroll
    for (int i = 0; i < 8; ++i) { s += v[i]; sq += v[i] * v[i]; }
#pragma unroll
    for (int off = 32; off >= 1; off >>= 1) {
        s += __shfl_xor(s, off);
        sq += __shfl_xor(sq, off);
    }
    __shared__ float sh[8];
    const int lane = tid & 63, wv = tid >> 6;
    if (lane == 0) { sh[wv] = s; sh[4 + wv] = sq; }
    __syncthreads();
    s = sh[0] + sh[1] + sh[2] + sh[3];
    sq = sh[4] + sh[5] + sh[6] + sh[7];

    const float invD = 1.0f / 2048.0f;
    const float mu = s * invD;
    const float rs = rsqrtf(sq * invD - mu * mu + 1e-5f);

    float4 g0 = *(const float4*)(gamma + c);
    float4 g1 = *(const float4*)(gamma + c + 4);
    float4 b0 = *(const float4*)(beta + c);
    float4 b1 = *(const float4*)(beta + c + 4);
    float gg[8] = {g0.x, g0.y, g0.z, g0.w, g1.x, g1.y, g1.z, g1.w};
    float bb[8] = {b0.x, b0.y, b0.z, b0.w, b1.x, b1.y, b1.z, b1.w};

    float o[8];
#pragma unroll
    for (int i = 0; i < 8; ++i) o[i] = (v[i] - mu) * rs * gg[i] + bb[i];
    *(float4*)(out + base)     = make_float4(o[0], o[1], o[2], o[3]);
    *(float4*)(out + base + 4) = make_float4(o[4], o[5], o[6], o[7]);
}

// ---------------------------------------------------------------------------
extern "C" void kernel_launch(void* const* d_in, const int* in_sizes, int n_in,
                              void* d_out, int out_size, void* d_ws, size_t ws_size,
                              hipStream_t stream)
{
    const float* e0   = (const float*)d_in[0];
    const float* e1   = (const float*)d_in[1];
    const float* e2   = (const float*)d_in[2];
    const float* e3   = (const float*)d_in[3];
    const float* qual = (const float*)d_in[4];
    const float* Wq   = (const float*)d_in[5];
    const float* bq   = (const float*)d_in[6];
    const float* Wk   = (const float*)d_in[7];
    const float* bk   = (const float*)d_in[8];
    const float* Wv   = (const float*)d_in[9];
    const float* bv   = (const float*)d_in[10];
    const float* Wo   = (const float*)d_in[11];
    const float* bo   = (const float*)d_in[12];
    const float* gm   = (const float*)d_in[13];
    const float* bt   = (const float*)d_in[14];

    const size_t WD = (size_t)DD * DD;            // 4,194,304
    const size_t MQ = (size_t)BB * NTT * DD;      // 33,554,432

    // workspace: Q(67.1MB) K(67.1MB) V(67.1MB) Wbuf(8.4MB) = 209.7MB total
    u16* Qbuf = (u16*)d_ws;
    u16* Kbuf = Qbuf + MQ;
    u16* Vbuf = Kbuf + MQ;
    u16* Wbuf = Vbuf + MQ;
    float* Y  = (float*)Kbuf;                     // f32 33.5MB, Kbuf dead post-attn

    // Q projection
    cvt_kernel<<<dim3((int)(WD / 2048)), 256, 0, stream>>>(Wq, Wbuf, (int)WD);
    qkv_gemm<<<dim3(128, 16), 256, 0, stream>>>(e0, e1, e2, e3, Wbuf, bq, Qbuf);
    // K projection
    cvt_kernel<<<dim3((int)(WD / 2048)), 256, 0, stream>>>(Wk, Wbuf, (int)WD);
    qkv_gemm<<<dim3(128, 16), 256, 0, stream>>>(e0, e1, e2, e3, Wbuf, bk, Kbuf);
    // V projection
    cvt_kernel<<<dim3((int)(WD / 2048)), 256, 0, stream>>>(Wv, Wbuf, (int)WD);
    qkv_gemm<<<dim3(128, 16), 256, 0, stream>>>(e0, e1, e2, e3, Wbuf, bv, Vbuf);

    // attention (ctx -> strided rows 4b of Qbuf)
    attn_kernel<<<dim3(16384), 256, 0, stream>>>(Qbuf, Kbuf, Vbuf, qual);

    // O projection
    cvt_kernel<<<dim3((int)(WD / 2048)), 256, 0, stream>>>(Wo, Wbuf, (int)WD);
    o_gemm<<<dim3(32, 16), 256, 0, stream>>>(Qbuf, Wbuf, bo, Y);

    // residual mean + LayerNorm
    ln_kernel<<<dim3(4096), 256, 0, stream>>>(Y, e0, e1, e2, e3, gm, bt, (float*)d_out);
}

// Round 4
// 1071.856 us; speedup vs baseline: 1.0539x; 1.0539x over previous
//
#include <hip/hip_runtime.h>
#include <cstdint>
#include <cstddef>

// Problem constants
#define BB 4096
#define DD 2048
#define NHH 16
#define NTT 4
#define DKK 128

using u16 = unsigned short;
using u32 = unsigned int;

typedef __bf16 bf16x8 __attribute__((ext_vector_type(8)));
typedef float f32x4 __attribute__((ext_vector_type(4)));

__device__ __forceinline__ float b2f(u16 u) {
    union { float f; u32 i; } c; c.i = ((u32)u) << 16; return c.f;
}
__device__ __forceinline__ u16 f2b(float f) {
    union { float f; u32 i; } c; c.f = f;
    u32 x = c.i;
    u32 r = (x + 0x7fffu + ((x >> 16) & 1u)) >> 16;  // RNE
    return (u16)r;
}
// pack two f32 -> two bf16 (round-half-up via +0x8000, then v_perm byte select)
__device__ __forceinline__ u32 pk(float lo, float hi) {
    u32 a = __builtin_bit_cast(u32, lo) + 0x8000u;
    u32 b = __builtin_bit_cast(u32, hi) + 0x8000u;
    return __builtin_amdgcn_perm(b, a, 0x07060302u);  // {b[31:16], a[31:16]}
}

__device__ __forceinline__ void load_lds16(const void* g, void* l) {
    __builtin_amdgcn_global_load_lds((const __attribute__((address_space(1))) void*)g,
                                     (__attribute__((address_space(3))) void*)l,
                                     16, 0, 0);
}

// ---------------------------------------------------------------------------
// Kernel 0: f32 -> bf16 conversion, 8 elements/thread (used for Wo only).
// ---------------------------------------------------------------------------
__global__ __launch_bounds__(256) void cvt_kernel(const float* __restrict__ src,
                                                  u16* __restrict__ dst, int n)
{
    const int i = (blockIdx.x * 256 + threadIdx.x) * 8;
    if (i + 7 >= n) {
        for (int j = i; j < n; ++j) dst[j] = f2b(src[j]);
        return;
    }
    float4 a = *(const float4*)(src + i);
    float4 b = *(const float4*)(src + i + 4);
    *(uint4*)(dst + i) = make_uint4(pk(a.x, a.y), pk(a.z, a.w),
                                    pk(b.x, b.y), pk(b.z, b.w));
}

// ---------------------------------------------------------------------------
// Kernel 1: fused QKV projection, one dispatch.
// bid = m*48 + j,  j = which*16 + nidx  (n/which fastest -> per-XCD A reuse).
// A rows m=(b*4+t) from e_t (f32->bf16 in-register), B from W_f32 likewise.
// Staging writes are lane-contiguous 16B (conflict-free ds_write_b128).
// 128x128 tile, BK=32, 16x16x32 bf16 MFMA, register prefetch of next K-slab.
// ---------------------------------------------------------------------------
__global__ __launch_bounds__(256) void qkv_fused(
    const float* __restrict__ e0, const float* __restrict__ e1,
    const float* __restrict__ e2, const float* __restrict__ e3,
    const float* __restrict__ Wq, const float* __restrict__ Wk,
    const float* __restrict__ Wv,
    const float* __restrict__ bq, const float* __restrict__ bk,
    const float* __restrict__ bv,
    u16* __restrict__ Qo, u16* __restrict__ Ko, u16* __restrict__ Vo)
{
    __shared__ __align__(16) u16 As[128 * 32];
    __shared__ __align__(16) u16 Bs[128 * 32];

    const int tid = threadIdx.x;
    const int bid = blockIdx.x;
    const int m = bid / 48;
    const int j = bid - m * 48;
    const int which = j >> 4;
    const int n0 = (j & 15) * 128;
    const int m0 = m * 128;

    const float* W   = (which == 0) ? Wq : (which == 1) ? Wk : Wv;
    const float* bia = (which == 0) ? bq : (which == 1) ? bk : bv;
    u16* C           = (which == 0) ? Qo : (which == 1) ? Ko : Vo;

    // staging coords: thread covers LDS rows rs and rs+64, k cols ks..ks+8
    const int rs = tid >> 2;          // 0..63
    const int ks = (tid & 3) * 8;     // 0,8,16,24
    const int ma = m0 + rs;
    const int ta = ma & 3;
    const float* ea = (ta == 0) ? e0 : (ta == 1) ? e1 : (ta == 2) ? e2 : e3;
    const float* srcA1 = ea + (size_t)(ma >> 2) * DD + ks;
    const float* srcA2 = srcA1 + (size_t)16 * DD;    // +64 M rows, same e_t
    const float* srcB1 = W + (size_t)(n0 + rs) * DD + ks;
    const float* srcB2 = srcB1 + (size_t)64 * DD;

    // lane-contiguous LDS destinations: byte tid*16 == row(tid>>2)*64 + (tid&3)*16
    uint4* dA1 = (uint4*)((char*)As + tid * 16);
    uint4* dA2 = (uint4*)((char*)As + 4096 + tid * 16);
    uint4* dB1 = (uint4*)((char*)Bs + tid * 16);
    uint4* dB2 = (uint4*)((char*)Bs + 4096 + tid * 16);

    const int lane = tid & 63;
    const int wave = tid >> 6;
    const int wm = (wave >> 1) * 64;
    const int wn = (wave & 1) * 64;
    const int lrow = lane & 15;
    const int lk = (lane >> 4) * 8;

    f32x4 acc[4][4] = {};

    // prologue: prefetch first K-slab (8 x float4 per thread)
    float4 pa0 = *(const float4*)(srcA1);
    float4 pa1 = *(const float4*)(srcA1 + 4);
    float4 pa2 = *(const float4*)(srcA2);
    float4 pa3 = *(const float4*)(srcA2 + 4);
    float4 pb0 = *(const float4*)(srcB1);
    float4 pb1 = *(const float4*)(srcB1 + 4);
    float4 pb2 = *(const float4*)(srcB2);
    float4 pb3 = *(const float4*)(srcB2 + 4);

    for (int k0 = 0; k0 < DD; k0 += 32) {
        __syncthreads();   // prior iteration's fragment reads complete
        *dA1 = make_uint4(pk(pa0.x, pa0.y), pk(pa0.z, pa0.w),
                          pk(pa1.x, pa1.y), pk(pa1.z, pa1.w));
        *dA2 = make_uint4(pk(pa2.x, pa2.y), pk(pa2.z, pa2.w),
                          pk(pa3.x, pa3.y), pk(pa3.z, pa3.w));
        *dB1 = make_uint4(pk(pb0.x, pb0.y), pk(pb0.z, pb0.w),
                          pk(pb1.x, pb1.y), pk(pb1.z, pb1.w));
        *dB2 = make_uint4(pk(pb2.x, pb2.y), pk(pb2.z, pb2.w),
                          pk(pb3.x, pb3.y), pk(pb3.z, pb3.w));
        __syncthreads();   // staging visible

        if (k0 + 32 < DD) {   // prefetch next slab; MFMA below hides latency
            srcA1 += 32; srcA2 += 32; srcB1 += 32; srcB2 += 32;
            pa0 = *(const float4*)(srcA1);
            pa1 = *(const float4*)(srcA1 + 4);
            pa2 = *(const float4*)(srcA2);
            pa3 = *(const float4*)(srcA2 + 4);
            pb0 = *(const float4*)(srcB1);
            pb1 = *(const float4*)(srcB1 + 4);
            pb2 = *(const float4*)(srcB2);
            pb3 = *(const float4*)(srcB2 + 4);
        }

        bf16x8 af[4], bfr[4];
#pragma unroll
        for (int i = 0; i < 4; ++i)
            af[i] = *(const bf16x8*)(As + (wm + i * 16 + lrow) * 32 + lk);
#pragma unroll
        for (int i = 0; i < 4; ++i)
            bfr[i] = *(const bf16x8*)(Bs + (wn + i * 16 + lrow) * 32 + lk);
#pragma unroll
        for (int mi = 0; mi < 4; ++mi)
#pragma unroll
            for (int ni = 0; ni < 4; ++ni)
                acc[mi][ni] = __builtin_amdgcn_mfma_f32_16x16x32_bf16(af[mi], bfr[ni], acc[mi][ni], 0, 0, 0);
    }

    // epilogue: C/D layout col=lane&15, row=(lane>>4)*4+reg  [m89-verified]
#pragma unroll
    for (int mi = 0; mi < 4; ++mi) {
#pragma unroll
        for (int r = 0; r < 4; ++r) {
            const int grow = m0 + wm + mi * 16 + (lane >> 4) * 4 + r;
#pragma unroll
            for (int ni = 0; ni < 4; ++ni) {
                const int gcol = n0 + wn + ni * 16 + (lane & 15);
                C[(size_t)grow * DD + gcol] = f2b(acc[mi][ni][r] + bia[gcol]);
            }
        }
    }
}

// ---------------------------------------------------------------------------
// Kernel 2: attention per (b,h), one wave each.  Softmax over 4 keys with
// quality gating; token-mean folded into key weights.  ctx written STRIDED
// into QC row 4b (race-free: wave (b,h) owns rows 4b..4b+3 x its col slice).
// ---------------------------------------------------------------------------
__global__ __launch_bounds__(256) void attn_kernel(
    u16* QC,                                   // Q buffer, NOT restrict (read+write)
    const u16* __restrict__ K, const u16* __restrict__ V,
    const float* __restrict__ qual)
{
    const int tid = threadIdx.x;
    const int lane = tid & 63;
    const int wid = tid >> 6;
    const int p = blockIdx.x * 4 + wid;        // 0..65535
    const int b = p >> 4;
    const int h = p & 15;
    const int col = h * 128 + lane * 2;

    float2 q[4], k[4], v[4];
#pragma unroll
    for (int t = 0; t < 4; ++t) {
        const size_t off = (size_t)(b * 4 + t) * DD + col;
        u32 uq = *(const u32*)(QC + off);
        u32 uk = *(const u32*)(K + off);
        u32 uv = *(const u32*)(V + off);
        q[t] = make_float2(b2f((u16)uq), b2f((u16)(uq >> 16)));
        k[t] = make_float2(b2f((u16)uk), b2f((u16)(uk >> 16)));
        v[t] = make_float2(b2f((u16)uv), b2f((u16)(uv >> 16)));
    }

    float s[4][4];
#pragma unroll
    for (int t = 0; t < 4; ++t)
#pragma unroll
        for (int j = 0; j < 4; ++j)
            s[t][j] = q[t].x * k[j].x + q[t].y * k[j].y;

#pragma unroll
    for (int off = 32; off >= 1; off >>= 1)
#pragma unroll
        for (int t = 0; t < 4; ++t)
#pragma unroll
            for (int j = 0; j < 4; ++j)
                s[t][j] += __shfl_xor(s[t][j], off);

    const float scale = 0.08838834764831845f;   // 1/sqrt(128)
    float qj[4];
#pragma unroll
    for (int j = 0; j < 4; ++j) qj[j] = qual[b * 4 + j] * scale;

    float wsum[4] = {0.f, 0.f, 0.f, 0.f};
#pragma unroll
    for (int t = 0; t < 4; ++t) {
        float sm[4]; float mx = -1e30f;
#pragma unroll
        for (int j = 0; j < 4; ++j) { sm[j] = s[t][j] * qj[j]; mx = fmaxf(mx, sm[j]); }
        float ex[4]; float se = 0.f;
#pragma unroll
        for (int j = 0; j < 4; ++j) { ex[j] = __expf(sm[j] - mx); se += ex[j]; }
        float inv = 1.0f / se;
#pragma unroll
        for (int j = 0; j < 4; ++j) wsum[j] += ex[j] * inv;
    }

    float cx = 0.f, cy = 0.f;
#pragma unroll
    for (int j = 0; j < 4; ++j) { cx += wsum[j] * v[j].x; cy += wsum[j] * v[j].y; }
    cx *= 0.25f; cy *= 0.25f;

    // strided ctx write: row 4b of QC (after all QC reads above)
    *(u32*)(QC + (size_t)(b * 4) * DD + col) = (u32)f2b(cx) | ((u32)f2b(cy) << 16);
}

// ---------------------------------------------------------------------------
// Kernel 3: O-projection.  A = ctx strided (row m at QC + 4m*DD), B = Wbuf.
// Y (f32) = A @ Wo^T + bo.
// ---------------------------------------------------------------------------
__global__ __launch_bounds__(256) void o_gemm(
    const u16* __restrict__ A, const u16* __restrict__ W,
    const float* __restrict__ bia, float* __restrict__ Y)
{
    __shared__ __align__(16) u16 As[128 * 32];
    __shared__ __align__(16) u16 Bs[128 * 32];

    const int tid = threadIdx.x;
    const int m0 = blockIdx.x * 128;
    const int n0 = blockIdx.y * 128;

    const int rb = tid >> 2;
    const int kb = (tid & 3) * 8;
    const u16* srcA1 = A + (size_t)(4 * (m0 + rb)) * DD + kb;   // strided rows
    const u16* srcA2 = srcA1 + (size_t)(4 * 64) * DD;
    const u16* srcB1 = W + (size_t)(n0 + rb) * DD + kb;
    const u16* srcB2 = srcB1 + (size_t)64 * DD;

    const int wave = tid >> 6;
    char* ldsA1 = (char*)As + wave * 1024;
    char* ldsA2 = (char*)As + 4096 + wave * 1024;
    char* ldsB1 = (char*)Bs + wave * 1024;
    char* ldsB2 = (char*)Bs + 4096 + wave * 1024;

    const int lane = tid & 63;
    const int wm = (wave >> 1) * 64;
    const int wn = (wave & 1) * 64;
    const int lrow = lane & 15;
    const int lk = (lane >> 4) * 8;

    f32x4 acc[4][4] = {};

    for (int k0 = 0; k0 < DD; k0 += 32) {
        __syncthreads();
        load_lds16(srcA1, ldsA1);
        load_lds16(srcA2, ldsA2);
        load_lds16(srcB1, ldsB1);
        load_lds16(srcB2, ldsB2);
        srcA1 += 32; srcA2 += 32; srcB1 += 32; srcB2 += 32;
        __syncthreads();

        bf16x8 af[4], bfr[4];
#pragma unroll
        for (int i = 0; i < 4; ++i)
            af[i] = *(const bf16x8*)(As + (wm + i * 16 + lrow) * 32 + lk);
#pragma unroll
        for (int i = 0; i < 4; ++i)
            bfr[i] = *(const bf16x8*)(Bs + (wn + i * 16 + lrow) * 32 + lk);
#pragma unroll
        for (int mi = 0; mi < 4; ++mi)
#pragma unroll
            for (int ni = 0; ni < 4; ++ni)
                acc[mi][ni] = __builtin_amdgcn_mfma_f32_16x16x32_bf16(af[mi], bfr[ni], acc[mi][ni], 0, 0, 0);
    }

#pragma unroll
    for (int mi = 0; mi < 4; ++mi) {
#pragma unroll
        for (int r = 0; r < 4; ++r) {
            const int grow = m0 + wm + mi * 16 + (lane >> 4) * 4 + r;
#pragma unroll
            for (int ni = 0; ni < 4; ++ni) {
                const int gcol = n0 + wn + ni * 16 + (lane & 15);
                Y[(size_t)grow * DD + gcol] = acc[mi][ni][r] + bia[gcol];
            }
        }
    }
}

// ---------------------------------------------------------------------------
// Kernel 4: residual mean + LayerNorm.  One block per row; all f32 I/O.
// ---------------------------------------------------------------------------
__global__ __launch_bounds__(256) void ln_kernel(
    const float* __restrict__ Y,
    const float* __restrict__ e0, const float* __restrict__ e1,
    const float* __restrict__ e2, const float* __restrict__ e3,
    const float* __restrict__ gamma, const float* __restrict__ beta,
    float* __restrict__ out)
{
    const int r = blockIdx.x;
    const int tid = threadIdx.x;
    const int c = tid * 8;
    const size_t base = (size_t)r * DD + c;

    float v[8];
    {
        float4 y0 = *(const float4*)(Y + base);
        float4 y1 = *(const float4*)(Y + base + 4);
        float a[8] = {0, 0, 0, 0, 0, 0, 0, 0};
        const float* eps[4] = {e0, e1, e2, e3};
#pragma unroll
        for (int q = 0; q < 4; ++q) {
            float4 p0 = *(const float4*)(eps[q] + base);
            float4 p1 = *(const float4*)(eps[q] + base + 4);
            a[0] += p0.x; a[1] += p0.y; a[2] += p0.z; a[3] += p0.w;
            a[4] += p1.x; a[5] += p1.y; a[6] += p1.z; a[7] += p1.w;
        }
        float yv[8] = {y0.x, y0.y, y0.z, y0.w, y1.x, y1.y, y1.z, y1.w};
#pragma unroll
        for (int i = 0; i < 8; ++i) v[i] = yv[i] + 0.25f * a[i];
    }

    float s = 0.f, sq = 0.f;
#pragma unroll
    for (int i = 0; i < 8; ++i) { s += v[i]; sq += v[i] * v[i]; }
#pragma unroll
    for (int off = 32; off >= 1; off >>= 1) {
        s += __shfl_xor(s, off);
        sq += __shfl_xor(sq, off);
    }
    __shared__ float sh[8];
    const int lane = tid & 63, wv = tid >> 6;
    if (lane == 0) { sh[wv] = s; sh[4 + wv] = sq; }
    __syncthreads();
    s = sh[0] + sh[1] + sh[2] + sh[3];
    sq = sh[4] + sh[5] + sh[6] + sh[7];

    const float invD = 1.0f / 2048.0f;
    const float mu = s * invD;
    const float rs = rsqrtf(sq * invD - mu * mu + 1e-5f);

    float4 g0 = *(const float4*)(gamma + c);
    float4 g1 = *(const float4*)(gamma + c + 4);
    float4 b0 = *(const float4*)(beta + c);
    float4 b1 = *(const float4*)(beta + c + 4);
    float gg[8] = {g0.x, g0.y, g0.z, g0.w, g1.x, g1.y, g1.z, g1.w};
    float bb[8] = {b0.x, b0.y, b0.z, b0.w, b1.x, b1.y, b1.z, b1.w};

    float o[8];
#pragma unroll
    for (int i = 0; i < 8; ++i) o[i] = (v[i] - mu) * rs * gg[i] + bb[i];
    *(float4*)(out + base)     = make_float4(o[0], o[1], o[2], o[3]);
    *(float4*)(out + base + 4) = make_float4(o[4], o[5], o[6], o[7]);
}

// ---------------------------------------------------------------------------
extern "C" void kernel_launch(void* const* d_in, const int* in_sizes, int n_in,
                              void* d_out, int out_size, void* d_ws, size_t ws_size,
                              hipStream_t stream)
{
    const float* e0   = (const float*)d_in[0];
    const float* e1   = (const float*)d_in[1];
    const float* e2   = (const float*)d_in[2];
    const float* e3   = (const float*)d_in[3];
    const float* qual = (const float*)d_in[4];
    const float* Wq   = (const float*)d_in[5];
    const float* bq   = (const float*)d_in[6];
    const float* Wk   = (const float*)d_in[7];
    const float* bk   = (const float*)d_in[8];
    const float* Wv   = (const float*)d_in[9];
    const float* bv   = (const float*)d_in[10];
    const float* Wo   = (const float*)d_in[11];
    const float* bo   = (const float*)d_in[12];
    const float* gm   = (const float*)d_in[13];
    const float* bt   = (const float*)d_in[14];

    const size_t WD = (size_t)DD * DD;            // 4,194,304
    const size_t MQ = (size_t)BB * NTT * DD;      // 33,554,432

    // workspace: Q(67.1MB) K(67.1MB) V(67.1MB) Wbuf(8.4MB) = 209.7MB total
    u16* Qbuf = (u16*)d_ws;
    u16* Kbuf = Qbuf + MQ;
    u16* Vbuf = Kbuf + MQ;
    u16* Wbuf = Vbuf + MQ;
    float* Y  = (float*)Kbuf;                     // f32 33.5MB, Kbuf dead post-attn

    // fused QKV projection (single dispatch; n/which fastest for per-XCD A reuse)
    qkv_fused<<<dim3(6144), 256, 0, stream>>>(e0, e1, e2, e3, Wq, Wk, Wv,
                                              bq, bk, bv, Qbuf, Kbuf, Vbuf);

    // attention (ctx -> strided rows 4b of Qbuf)
    attn_kernel<<<dim3(16384), 256, 0, stream>>>(Qbuf, Kbuf, Vbuf, qual);

    // O projection (Wo via bf16 cvt into Wbuf)
    cvt_kernel<<<dim3((int)(WD / 2048)), 256, 0, stream>>>(Wo, Wbuf, (int)WD);
    o_gemm<<<dim3(32, 16), 256, 0, stream>>>(Qbuf, Wbuf, bo, Y);

    // residual mean + LayerNorm
    ln_kernel<<<dim3(4096), 256, 0, stream>>>(Y, e0, e1, e2, e3, gm, bt, (float*)d_out);
}

// Round 5
// 836.895 us; speedup vs baseline: 1.3498x; 1.2808x over previous
//
#include <hip/hip_runtime.h>
#include <cstdint>
#include <cstddef>

// Problem constants
#define BB 4096
#define DD 2048
#define NHH 16
#define NTT 4
#define DKK 128

using u16 = unsigned short;
using u32 = unsigned int;

typedef __bf16 bf16x8 __attribute__((ext_vector_type(8)));
typedef float f32x4 __attribute__((ext_vector_type(4)));

__device__ __forceinline__ float b2f(u16 u) {
    union { float f; u32 i; } c; c.i = ((u32)u) << 16; return c.f;
}
__device__ __forceinline__ u16 f2b(float f) {
    union { float f; u32 i; } c; c.f = f;
    u32 x = c.i;
    u32 r = (x + 0x7fffu + ((x >> 16) & 1u)) >> 16;  // RNE
    return (u16)r;
}
// pack two f32 -> two bf16 (round-half-up via +0x8000, v_perm byte select)
__device__ __forceinline__ u32 pk(float lo, float hi) {
    u32 a = __builtin_bit_cast(u32, lo) + 0x8000u;
    u32 b = __builtin_bit_cast(u32, hi) + 0x8000u;
    return __builtin_amdgcn_perm(b, a, 0x07060302u);  // {b[31:16], a[31:16]}
}

__device__ __forceinline__ void load_lds16(const void* g, void* l) {
    __builtin_amdgcn_global_load_lds((const __attribute__((address_space(1))) void*)g,
                                     (__attribute__((address_space(3))) void*)l,
                                     16, 0, 0);
}

// ---------------------------------------------------------------------------
// cvt_e: e_t[b] (f32) -> Ebf row (4b+t) (bf16).  One block per M-row.
// ---------------------------------------------------------------------------
__global__ __launch_bounds__(256) void cvt_e(
    const float* __restrict__ e0, const float* __restrict__ e1,
    const float* __restrict__ e2, const float* __restrict__ e3,
    u16* __restrict__ Ebf)
{
    const int g = blockIdx.x;            // 0..16383  (m-row = b*4 + t)
    const int t = g & 3, b = g >> 2;
    const float* src = ((t == 0) ? e0 : (t == 1) ? e1 : (t == 2) ? e2 : e3)
                       + (size_t)b * DD;
    u16* dst = Ebf + (size_t)g * DD;
    const int i = threadIdx.x * 8;
    float4 a = *(const float4*)(src + i);
    float4 c = *(const float4*)(src + i + 4);
    *(uint4*)(dst + i) = make_uint4(pk(a.x, a.y), pk(a.z, a.w),
                                    pk(c.x, c.y), pk(c.z, c.w));
}

// ---------------------------------------------------------------------------
// cvt_kernel: generic f32 -> bf16, 8 elements/thread.
// ---------------------------------------------------------------------------
__global__ __launch_bounds__(256) void cvt_kernel(const float* __restrict__ src,
                                                  u16* __restrict__ dst, int n)
{
    const int i = (blockIdx.x * 256 + threadIdx.x) * 8;
    if (i + 7 >= n) {
        for (int j = i; j < n; ++j) dst[j] = f2b(src[j]);
        return;
    }
    float4 a = *(const float4*)(src + i);
    float4 b = *(const float4*)(src + i + 4);
    *(uint4*)(dst + i) = make_uint4(pk(a.x, a.y), pk(a.z, a.w),
                                    pk(b.x, b.y), pk(b.z, b.w));
}

// ---------------------------------------------------------------------------
// qk_gemm: fused Q+K projections, pure m97 structure (A and B async via
// global_load_lds 16B).  bid = m*32 + j; j = which*16 + nidx (n-fastest for
// per-XCD A reuse).  128x128 tile, BK=32, 16x16x32 bf16 MFMA.
// ---------------------------------------------------------------------------
__global__ __launch_bounds__(256) void qk_gemm(
    const u16* __restrict__ Ebf, const u16* __restrict__ Wbf,
    const float* __restrict__ bq, const float* __restrict__ bk,
    u16* __restrict__ Qo, u16* __restrict__ Ko)
{
    __shared__ __align__(16) u16 As[128 * 32];
    __shared__ __align__(16) u16 Bs[128 * 32];

    const int tid = threadIdx.x;
    const int bid = blockIdx.x;
    const int m0 = (bid >> 5) * 128;
    const int j = bid & 31;
    const int which = j >> 4;
    const int n0 = (j & 15) * 128;

    const u16* W     = Wbf + (size_t)which * DD * DD;
    const float* bia = which ? bk : bq;
    u16* C           = which ? Ko : Qo;

    const int rs = tid >> 2;          // LDS row 0..63 (and +64)
    const int ks = (tid & 3) * 8;
    const u16* srcA1 = Ebf + (size_t)(m0 + rs) * DD + ks;
    const u16* srcA2 = srcA1 + (size_t)64 * DD;
    const u16* srcB1 = W + (size_t)(n0 + rs) * DD + ks;
    const u16* srcB2 = srcB1 + (size_t)64 * DD;

    const int wave = tid >> 6;
    char* ldsA1 = (char*)As + wave * 1024;
    char* ldsA2 = (char*)As + 4096 + wave * 1024;
    char* ldsB1 = (char*)Bs + wave * 1024;
    char* ldsB2 = (char*)Bs + 4096 + wave * 1024;

    const int lane = tid & 63;
    const int wm = (wave >> 1) * 64;
    const int wn = (wave & 1) * 64;
    const int lrow = lane & 15;
    const int lk = (lane >> 4) * 8;

    f32x4 acc[4][4] = {};

    for (int k0 = 0; k0 < DD; k0 += 32) {
        __syncthreads();
        load_lds16(srcA1, ldsA1);
        load_lds16(srcA2, ldsA2);
        load_lds16(srcB1, ldsB1);
        load_lds16(srcB2, ldsB2);
        srcA1 += 32; srcA2 += 32; srcB1 += 32; srcB2 += 32;
        __syncthreads();

        bf16x8 af[4], bfr[4];
#pragma unroll
        for (int i = 0; i < 4; ++i)
            af[i] = *(const bf16x8*)(As + (wm + i * 16 + lrow) * 32 + lk);
#pragma unroll
        for (int i = 0; i < 4; ++i)
            bfr[i] = *(const bf16x8*)(Bs + (wn + i * 16 + lrow) * 32 + lk);
#pragma unroll
        for (int mi = 0; mi < 4; ++mi)
#pragma unroll
            for (int ni = 0; ni < 4; ++ni)
                acc[mi][ni] = __builtin_amdgcn_mfma_f32_16x16x32_bf16(af[mi], bfr[ni], acc[mi][ni], 0, 0, 0);
    }

    // epilogue: C/D layout col=lane&15, row=(lane>>4)*4+reg  [m89-verified]
#pragma unroll
    for (int mi = 0; mi < 4; ++mi) {
#pragma unroll
        for (int r = 0; r < 4; ++r) {
            const int grow = m0 + wm + mi * 16 + (lane >> 4) * 4 + r;
#pragma unroll
            for (int ni = 0; ni < 4; ++ni) {
                const int gcol = n0 + wn + ni * 16 + (lane & 15);
                C[(size_t)grow * DD + gcol] = f2b(acc[mi][ni][r] + bia[gcol]);
            }
        }
    }
}

// ---------------------------------------------------------------------------
// attn_w: per (b,h) wave computes the 4 per-key combine weights
// wsum[j] = 0.25 * sum_t softmax_j(scores[t])  and stores them as float4.
// ---------------------------------------------------------------------------
__global__ __launch_bounds__(256) void attn_w(
    const u16* __restrict__ Q, const u16* __restrict__ K,
    const float* __restrict__ qual, float* __restrict__ wts)
{
    const int tid = threadIdx.x;
    const int lane = tid & 63;
    const int wid = tid >> 6;
    const int p = blockIdx.x * 4 + wid;        // 0..65535
    const int b = p >> 4;
    const int h = p & 15;
    const int col = h * 128 + lane * 2;

    float2 q[4], k[4];
#pragma unroll
    for (int t = 0; t < 4; ++t) {
        const size_t off = (size_t)(b * 4 + t) * DD + col;
        u32 uq = *(const u32*)(Q + off);
        u32 uk = *(const u32*)(K + off);
        q[t] = make_float2(b2f((u16)uq), b2f((u16)(uq >> 16)));
        k[t] = make_float2(b2f((u16)uk), b2f((u16)(uk >> 16)));
    }

    float s[4][4];
#pragma unroll
    for (int t = 0; t < 4; ++t)
#pragma unroll
        for (int j = 0; j < 4; ++j)
            s[t][j] = q[t].x * k[j].x + q[t].y * k[j].y;

#pragma unroll
    for (int off = 32; off >= 1; off >>= 1)
#pragma unroll
        for (int t = 0; t < 4; ++t)
#pragma unroll
            for (int j = 0; j < 4; ++j)
                s[t][j] += __shfl_xor(s[t][j], off);

    const float scale = 0.08838834764831845f;   // 1/sqrt(128)
    float qj[4];
#pragma unroll
    for (int j = 0; j < 4; ++j) qj[j] = qual[b * 4 + j] * scale;

    float wsum[4] = {0.f, 0.f, 0.f, 0.f};
#pragma unroll
    for (int t = 0; t < 4; ++t) {
        float sm[4]; float mx = -1e30f;
#pragma unroll
        for (int j = 0; j < 4; ++j) { sm[j] = s[t][j] * qj[j]; mx = fmaxf(mx, sm[j]); }
        float ex[4]; float se = 0.f;
#pragma unroll
        for (int j = 0; j < 4; ++j) { ex[j] = __expf(sm[j] - mx); se += ex[j]; }
        float inv = 0.25f / se;
#pragma unroll
        for (int j = 0; j < 4; ++j) wsum[j] += ex[j] * inv;
    }

    if (lane == 0)
        *(float4*)(wts + (size_t)(b * 16 + h) * 4) =
            make_float4(wsum[0], wsum[1], wsum[2], wsum[3]);
}

// ---------------------------------------------------------------------------
// vctx_gemm: V-projection with the attention combine fused into the epilogue.
// Tile n = one head (128 cols).  C-layout puts tokens t=0..3 of a given b in
// one lane's 4 acc registers -> ctx[b] = dot(wts[b][h], acc) + bv, per lane.
// A = Ebf (async), B = Wv bf16 (async).  V is never materialized.
// ---------------------------------------------------------------------------
__global__ __launch_bounds__(256) void vctx_gemm(
    const u16* __restrict__ Ebf, const u16* __restrict__ Wvbf,
    const float* __restrict__ wts, const float* __restrict__ bv,
    u16* __restrict__ ctx)
{
    __shared__ __align__(16) u16 As[128 * 32];
    __shared__ __align__(16) u16 Bs[128 * 32];

    const int tid = threadIdx.x;
    const int m0 = blockIdx.x * 128;
    const int h = blockIdx.y;            // head = n-tile
    const int n0 = h * 128;

    const int rs = tid >> 2;
    const int ks = (tid & 3) * 8;
    const u16* srcA1 = Ebf + (size_t)(m0 + rs) * DD + ks;
    const u16* srcA2 = srcA1 + (size_t)64 * DD;
    const u16* srcB1 = Wvbf + (size_t)(n0 + rs) * DD + ks;
    const u16* srcB2 = srcB1 + (size_t)64 * DD;

    const int wave = tid >> 6;
    char* ldsA1 = (char*)As + wave * 1024;
    char* ldsA2 = (char*)As + 4096 + wave * 1024;
    char* ldsB1 = (char*)Bs + wave * 1024;
    char* ldsB2 = (char*)Bs + 4096 + wave * 1024;

    const int lane = tid & 63;
    const int wm = (wave >> 1) * 64;
    const int wn = (wave & 1) * 64;
    const int lrow = lane & 15;
    const int lk = (lane >> 4) * 8;

    f32x4 acc[4][4] = {};

    for (int k0 = 0; k0 < DD; k0 += 32) {
        __syncthreads();
        load_lds16(srcA1, ldsA1);
        load_lds16(srcA2, ldsA2);
        load_lds16(srcB1, ldsB1);
        load_lds16(srcB2, ldsB2);
        srcA1 += 32; srcA2 += 32; srcB1 += 32; srcB2 += 32;
        __syncthreads();

        bf16x8 af[4], bfr[4];
#pragma unroll
        for (int i = 0; i < 4; ++i)
            af[i] = *(const bf16x8*)(As + (wm + i * 16 + lrow) * 32 + lk);
#pragma unroll
        for (int i = 0; i < 4; ++i)
            bfr[i] = *(const bf16x8*)(Bs + (wn + i * 16 + lrow) * 32 + lk);
#pragma unroll
        for (int mi = 0; mi < 4; ++mi)
#pragma unroll
            for (int ni = 0; ni < 4; ++ni)
                acc[mi][ni] = __builtin_amdgcn_mfma_f32_16x16x32_bf16(af[mi], bfr[ni], acc[mi][ni], 0, 0, 0);
    }

    // epilogue: rows 4q+r (r=reg) = tokens of batch b; combine with wts.
    const int q4 = (lane >> 4) * 4;
    const int colc = lane & 15;
#pragma unroll
    for (int mi = 0; mi < 4; ++mi) {
        const int b = (m0 + wm + mi * 16 + q4) >> 2;
        const float4 w = *(const float4*)(wts + (size_t)(b * 16 + h) * 4);
#pragma unroll
        for (int ni = 0; ni < 4; ++ni) {
            const int gcol = n0 + wn + ni * 16 + colc;
            float r = w.x * acc[mi][ni][0] + w.y * acc[mi][ni][1]
                    + w.z * acc[mi][ni][2] + w.w * acc[mi][ni][3] + bv[gcol];
            ctx[(size_t)b * DD + gcol] = f2b(r);
        }
    }
}

// ---------------------------------------------------------------------------
// o_gemm: Y (f32) = ctx @ Wo^T + bo.  Pure m97 structure, contiguous A.
// ---------------------------------------------------------------------------
__global__ __launch_bounds__(256) void o_gemm(
    const u16* __restrict__ A, const u16* __restrict__ W,
    const float* __restrict__ bia, float* __restrict__ Y)
{
    __shared__ __align__(16) u16 As[128 * 32];
    __shared__ __align__(16) u16 Bs[128 * 32];

    const int tid = threadIdx.x;
    const int m0 = blockIdx.x * 128;
    const int n0 = blockIdx.y * 128;

    const int rs = tid >> 2;
    const int ks = (tid & 3) * 8;
    const u16* srcA1 = A + (size_t)(m0 + rs) * DD + ks;
    const u16* srcA2 = srcA1 + (size_t)64 * DD;
    const u16* srcB1 = W + (size_t)(n0 + rs) * DD + ks;
    const u16* srcB2 = srcB1 + (size_t)64 * DD;

    const int wave = tid >> 6;
    char* ldsA1 = (char*)As + wave * 1024;
    char* ldsA2 = (char*)As + 4096 + wave * 1024;
    char* ldsB1 = (char*)Bs + wave * 1024;
    char* ldsB2 = (char*)Bs + 4096 + wave * 1024;

    const int lane = tid & 63;
    const int wm = (wave >> 1) * 64;
    const int wn = (wave & 1) * 64;
    const int lrow = lane & 15;
    const int lk = (lane >> 4) * 8;

    f32x4 acc[4][4] = {};

    for (int k0 = 0; k0 < DD; k0 += 32) {
        __syncthreads();
        load_lds16(srcA1, ldsA1);
        load_lds16(srcA2, ldsA2);
        load_lds16(srcB1, ldsB1);
        load_lds16(srcB2, ldsB2);
        srcA1 += 32; srcA2 += 32; srcB1 += 32; srcB2 += 32;
        __syncthreads();

        bf16x8 af[4], bfr[4];
#pragma unroll
        for (int i = 0; i < 4; ++i)
            af[i] = *(const bf16x8*)(As + (wm + i * 16 + lrow) * 32 + lk);
#pragma unroll
        for (int i = 0; i < 4; ++i)
            bfr[i] = *(const bf16x8*)(Bs + (wn + i * 16 + lrow) * 32 + lk);
#pragma unroll
        for (int mi = 0; mi < 4; ++mi)
#pragma unroll
            for (int ni = 0; ni < 4; ++ni)
                acc[mi][ni] = __builtin_amdgcn_mfma_f32_16x16x32_bf16(af[mi], bfr[ni], acc[mi][ni], 0, 0, 0);
    }

#pragma unroll
    for (int mi = 0; mi < 4; ++mi) {
#pragma unroll
        for (int r = 0; r < 4; ++r) {
            const int grow = m0 + wm + mi * 16 + (lane >> 4) * 4 + r;
#pragma unroll
            for (int ni = 0; ni < 4; ++ni) {
                const int gcol = n0 + wn + ni * 16 + (lane & 15);
                Y[(size_t)grow * DD + gcol] = acc[mi][ni][r] + bia[gcol];
            }
        }
    }
}

// ---------------------------------------------------------------------------
// ln_kernel: residual mean + LayerNorm.  One block per row; all f32 I/O.
// ---------------------------------------------------------------------------
__global__ __launch_bounds__(256) void ln_kernel(
    const float* __restrict__ Y,
    const float* __restrict__ e0, const float* __restrict__ e1,
    const float* __restrict__ e2, const float* __restrict__ e3,
    const float* __restrict__ gamma, const float* __restrict__ beta,
    float* __restrict__ out)
{
    const int r = blockIdx.x;
    const int tid = threadIdx.x;
    const int c = tid * 8;
    const size_t base = (size_t)r * DD + c;

    float v[8];
    {
        float4 y0 = *(const float4*)(Y + base);
        float4 y1 = *(const float4*)(Y + base + 4);
        float a[8] = {0, 0, 0, 0, 0, 0, 0, 0};
        const float* eps[4] = {e0, e1, e2, e3};
#pragma unroll
        for (int qq = 0; qq < 4; ++qq) {
            float4 p0 = *(const float4*)(eps[qq] + base);
            float4 p1 = *(const float4*)(eps[qq] + base + 4);
            a[0] += p0.x; a[1] += p0.y; a[2] += p0.z; a[3] += p0.w;
            a[4] += p1.x; a[5] += p1.y; a[6] += p1.z; a[7] += p1.w;
        }
        float yv[8] = {y0.x, y0.y, y0.z, y0.w, y1.x, y1.y, y1.z, y1.w};
#pragma unroll
        for (int i = 0; i < 8; ++i) v[i] = yv[i] + 0.25f * a[i];
    }

    float s = 0.f, sq = 0.f;
#pragma unroll
    for (int i = 0; i < 8; ++i) { s += v[i]; sq += v[i] * v[i]; }
#pragma unroll
    for (int off = 32; off >= 1; off >>= 1) {
        s += __shfl_xor(s, off);
        sq += __shfl_xor(sq, off);
    }
    __shared__ float sh[8];
    const int lane = tid & 63, wv = tid >> 6;
    if (lane == 0) { sh[wv] = s; sh[4 + wv] = sq; }
    __syncthreads();
    s = sh[0] + sh[1] + sh[2] + sh[3];
    sq = sh[4] + sh[5] + sh[6] + sh[7];

    const float invD = 1.0f / 2048.0f;
    const float mu = s * invD;
    const float rs = rsqrtf(sq * invD - mu * mu + 1e-5f);

    float4 g0 = *(const float4*)(gamma + c);
    float4 g1 = *(const float4*)(gamma + c + 4);
    float4 b0 = *(const float4*)(beta + c);
    float4 b1 = *(const float4*)(beta + c + 4);
    float gg[8] = {g0.x, g0.y, g0.z, g0.w, g1.x, g1.y, g1.z, g1.w};
    float bb[8] = {b0.x, b0.y, b0.z, b0.w, b1.x, b1.y, b1.z, b1.w};

    float o[8];
#pragma unroll
    for (int i = 0; i < 8; ++i) o[i] = (v[i] - mu) * rs * gg[i] + bb[i];
    *(float4*)(out + base)     = make_float4(o[0], o[1], o[2], o[3]);
    *(float4*)(out + base + 4) = make_float4(o[4], o[5], o[6], o[7]);
}

// ---------------------------------------------------------------------------
extern "C" void kernel_launch(void* const* d_in, const int* in_sizes, int n_in,
                              void* d_out, int out_size, void* d_ws, size_t ws_size,
                              hipStream_t stream)
{
    const float* e0   = (const float*)d_in[0];
    const float* e1   = (const float*)d_in[1];
    const float* e2   = (const float*)d_in[2];
    const float* e3   = (const float*)d_in[3];
    const float* qual = (const float*)d_in[4];
    const float* Wq   = (const float*)d_in[5];
    const float* bq   = (const float*)d_in[6];
    const float* Wk   = (const float*)d_in[7];
    const float* bk   = (const float*)d_in[8];
    const float* Wv   = (const float*)d_in[9];
    const float* bv   = (const float*)d_in[10];
    const float* Wo   = (const float*)d_in[11];
    const float* bo   = (const float*)d_in[12];
    const float* gm   = (const float*)d_in[13];
    const float* bt   = (const float*)d_in[14];

    const size_t WD = (size_t)DD * DD;            // 4,194,304
    const size_t MQ = (size_t)BB * NTT * DD;      // 33,554,432  (=4*ED)

    // workspace (u16 units): Ebf(67.1MB) Q(67.1) K(67.1) Wbf(16.8) = 218.1MB
    // == round-1-proven footprint.
    u16* Ebf = (u16*)d_ws;                        // MQ
    u16* Qb  = Ebf + MQ;                          // MQ
    u16* Kb  = Qb + MQ;                           // MQ
    u16* Wbf = Kb + MQ;                           // 2*WD (slot0, slot1)
    float* wts = (float*)(Wbf + WD);              // 1 MB, reuses slot1 post-qk
    u16* ctx = Qb;                                // Q dead after attn_w
    float* Y = (float*)Kb;                        // K dead after attn_w

    // stage 0: conversions
    cvt_e<<<dim3(16384), 256, 0, stream>>>(e0, e1, e2, e3, Ebf);
    cvt_kernel<<<dim3(2048), 256, 0, stream>>>(Wq, Wbf, (int)WD);
    cvt_kernel<<<dim3(2048), 256, 0, stream>>>(Wk, Wbf + WD, (int)WD);

    // stage 1: Q,K projections (fused, pure-async m97 structure)
    qk_gemm<<<dim3(4096), 256, 0, stream>>>(Ebf, Wbf, bq, bk, Qb, Kb);

    // stage 2: attention combine weights (1 MB)
    attn_w<<<dim3(16384), 256, 0, stream>>>(Qb, Kb, qual, wts);

    // stage 3: V projection fused with attention combine -> ctx (into Q region)
    cvt_kernel<<<dim3(2048), 256, 0, stream>>>(Wv, Wbf, (int)WD);   // slot0 reuse
    vctx_gemm<<<dim3(128, 16), 256, 0, stream>>>(Ebf, Wbf, wts, bv, ctx);

    // stage 4: O projection -> Y f32 (into K region)
    cvt_kernel<<<dim3(2048), 256, 0, stream>>>(Wo, Wbf, (int)WD);   // slot0 reuse
    o_gemm<<<dim3(32, 16), 256, 0, stream>>>(ctx, Wbf, bo, Y);

    // stage 5: residual mean + LayerNorm
    ln_kernel<<<dim3(4096), 256, 0, stream>>>(Y, e0, e1, e2, e3, gm, bt, (float*)d_out);
}

// Round 6
// 680.816 us; speedup vs baseline: 1.6592x; 1.2293x over previous
//
#include <hip/hip_runtime.h>
#include <cstdint>
#include <cstddef>

// Problem constants
#define BB 4096
#define DD 2048
#define NHH 16
#define NTT 4
#define DKK 128

using u16 = unsigned short;
using u32 = unsigned int;

typedef __bf16 bf16x8 __attribute__((ext_vector_type(8)));
typedef float f32x4 __attribute__((ext_vector_type(4)));

__device__ __forceinline__ float b2f(u16 u) {
    union { float f; u32 i; } c; c.i = ((u32)u) << 16; return c.f;
}
__device__ __forceinline__ u16 f2b(float f) {
    union { float f; u32 i; } c; c.f = f;
    u32 x = c.i;
    u32 r = (x + 0x7fffu + ((x >> 16) & 1u)) >> 16;  // RNE
    return (u16)r;
}
// pack two f32 -> two bf16 (round-half-up via +0x8000, v_perm byte select)
__device__ __forceinline__ u32 pk(float lo, float hi) {
    u32 a = __builtin_bit_cast(u32, lo) + 0x8000u;
    u32 b = __builtin_bit_cast(u32, hi) + 0x8000u;
    return __builtin_amdgcn_perm(b, a, 0x07060302u);  // {b[31:16], a[31:16]}
}

__device__ __forceinline__ void load_lds16(const void* g, void* l) {
    __builtin_amdgcn_global_load_lds((const __attribute__((address_space(1))) void*)g,
                                     (__attribute__((address_space(3))) void*)l,
                                     16, 0, 0);
}

// ---------------------------------------------------------------------------
// cvt_all: one dispatch converts e0..e3 -> Ebf (M-interleaved rows 4b+t) and
// Wq/Wk/Wv/Wo -> W4 (4 contiguous bf16 slots).
// blocks 0..16383: evidence rows.  blocks 16384..24575: weights (2048/blk).
// ---------------------------------------------------------------------------
__global__ __launch_bounds__(256) void cvt_all(
    const float* __restrict__ e0, const float* __restrict__ e1,
    const float* __restrict__ e2, const float* __restrict__ e3,
    const float* __restrict__ Wq, const float* __restrict__ Wk,
    const float* __restrict__ Wv, const float* __restrict__ Wo,
    u16* __restrict__ Ebf, u16* __restrict__ W4)
{
    const int blk = blockIdx.x;
    const float* src;
    u16* dst;
    size_t i;
    if (blk < 16384) {
        const int t = blk & 3, b = blk >> 2;
        src = ((t == 0) ? e0 : (t == 1) ? e1 : (t == 2) ? e2 : e3) + (size_t)b * DD;
        dst = Ebf + (size_t)blk * DD;
        i = threadIdx.x * 8;
    } else {
        const int wb = blk - 16384;          // 0..8191
        const int w = wb >> 11;              // 0..3
        src = (w == 0) ? Wq : (w == 1) ? Wk : (w == 2) ? Wv : Wo;
        dst = W4 + (size_t)w * DD * DD;
        i = (size_t)(wb & 2047) * 2048 + threadIdx.x * 8;
    }
    float4 a = *(const float4*)(src + i);
    float4 c = *(const float4*)(src + i + 4);
    *(uint4*)(dst + i) = make_uint4(pk(a.x, a.y), pk(a.z, a.w),
                                    pk(c.x, c.y), pk(c.z, c.w));
}

// ---------------------------------------------------------------------------
// qkv_attn: fused Q/K/V projection + quality-gated softmax + V-combine.
// grid (16, 128): x = head h (n-tile = 128 cols = one head), y = m-tile.
// Per block: 128x128x3 GEMM tile.  Wave w owns rows wm=w*32..w*32+31 and ALL
// 128 head cols -> per batch b, tokens 4b+t are the 4 regs of one lane and
// the full score dot reduces with 8 in-lane FMAs + 16-lane butterfly.
// Q/K/V and attention weights never touch global memory; writes ctx only.
// ---------------------------------------------------------------------------
__global__ __launch_bounds__(256, 2) void qkv_attn(
    const u16* __restrict__ Ebf,
    const u16* __restrict__ Wqb, const u16* __restrict__ Wkb,
    const u16* __restrict__ Wvb,
    const float* __restrict__ bq, const float* __restrict__ bk,
    const float* __restrict__ bv, const float* __restrict__ qual,
    u16* __restrict__ ctx)
{
    __shared__ __align__(16) u16 As[128 * 32];
    __shared__ __align__(16) u16 BQs[128 * 32];
    __shared__ __align__(16) u16 BKs[128 * 32];
    __shared__ __align__(16) u16 BVs[128 * 32];

    const int tid = threadIdx.x;
    const int h = blockIdx.x;            // head = n-tile
    const int m0 = blockIdx.y * 128;
    const int n0 = h * 128;

    // staging: thread covers rows rs and rs+64, k cols ks..ks+8 of each tile
    const int rs = tid >> 2;
    const int ks = (tid & 3) * 8;
    const u16* srcA1 = Ebf + (size_t)(m0 + rs) * DD + ks;
    const u16* srcA2 = srcA1 + (size_t)64 * DD;
    const u16* srcQ1 = Wqb + (size_t)(n0 + rs) * DD + ks;
    const u16* srcQ2 = srcQ1 + (size_t)64 * DD;
    const u16* srcK1 = Wkb + (size_t)(n0 + rs) * DD + ks;
    const u16* srcK2 = srcK1 + (size_t)64 * DD;
    const u16* srcV1 = Wvb + (size_t)(n0 + rs) * DD + ks;
    const u16* srcV2 = srcV1 + (size_t)64 * DD;

    const int wave = tid >> 6;
    char* ldsA1 = (char*)As  + wave * 1024;
    char* ldsA2 = (char*)As  + 4096 + wave * 1024;
    char* ldsQ1 = (char*)BQs + wave * 1024;
    char* ldsQ2 = (char*)BQs + 4096 + wave * 1024;
    char* ldsK1 = (char*)BKs + wave * 1024;
    char* ldsK2 = (char*)BKs + 4096 + wave * 1024;
    char* ldsV1 = (char*)BVs + wave * 1024;
    char* ldsV2 = (char*)BVs + 4096 + wave * 1024;

    const int lane = tid & 63;
    const int lrow = lane & 15;
    const int lk = (lane >> 4) * 8;
    const int wm = wave * 32;            // wave's 32 M-rows; cols = all 128

    f32x4 aQ[2][8] = {};
    f32x4 aK[2][8] = {};
    f32x4 aV[2][8] = {};

    for (int k0 = 0; k0 < DD; k0 += 32) {
        __syncthreads();
        load_lds16(srcA1, ldsA1);
        load_lds16(srcA2, ldsA2);
        load_lds16(srcQ1, ldsQ1);
        load_lds16(srcQ2, ldsQ2);
        load_lds16(srcK1, ldsK1);
        load_lds16(srcK2, ldsK2);
        load_lds16(srcV1, ldsV1);
        load_lds16(srcV2, ldsV2);
        srcA1 += 32; srcA2 += 32; srcQ1 += 32; srcQ2 += 32;
        srcK1 += 32; srcK2 += 32; srcV1 += 32; srcV2 += 32;
        __syncthreads();

        bf16x8 af0 = *(const bf16x8*)(As + (wm + lrow) * 32 + lk);
        bf16x8 af1 = *(const bf16x8*)(As + (wm + 16 + lrow) * 32 + lk);
#pragma unroll
        for (int ni = 0; ni < 8; ++ni) {
            const int boff = (ni * 16 + lrow) * 32 + lk;
            bf16x8 bqf = *(const bf16x8*)(BQs + boff);
            bf16x8 bkf = *(const bf16x8*)(BKs + boff);
            bf16x8 bvf = *(const bf16x8*)(BVs + boff);
            aQ[0][ni] = __builtin_amdgcn_mfma_f32_16x16x32_bf16(af0, bqf, aQ[0][ni], 0, 0, 0);
            aQ[1][ni] = __builtin_amdgcn_mfma_f32_16x16x32_bf16(af1, bqf, aQ[1][ni], 0, 0, 0);
            aK[0][ni] = __builtin_amdgcn_mfma_f32_16x16x32_bf16(af0, bkf, aK[0][ni], 0, 0, 0);
            aK[1][ni] = __builtin_amdgcn_mfma_f32_16x16x32_bf16(af1, bkf, aK[1][ni], 0, 0, 0);
            aV[0][ni] = __builtin_amdgcn_mfma_f32_16x16x32_bf16(af0, bvf, aV[0][ni], 0, 0, 0);
            aV[1][ni] = __builtin_amdgcn_mfma_f32_16x16x32_bf16(af1, bvf, aV[1][ni], 0, 0, 0);
        }
    }

    // ---- epilogue: scores -> softmax -> V combine (all in-registers) ----
    const int quad = lane >> 4;
    const int lcol = lane & 15;

    float qb[8], kb[8], vb[8];
#pragma unroll
    for (int ni = 0; ni < 8; ++ni) {
        const int col = n0 + ni * 16 + lcol;
        qb[ni] = bq[col]; kb[ni] = bk[col]; vb[ni] = bv[col];
    }

#pragma unroll
    for (int mi = 0; mi < 2; ++mi) {
        // batch handled by this lane-quad for this mi
        const int bbat = (m0 >> 2) + wave * 8 + mi * 4 + quad;

        float ps[4][4];
#pragma unroll
        for (int t = 0; t < 4; ++t)
#pragma unroll
            for (int j = 0; j < 4; ++j) ps[t][j] = 0.f;

#pragma unroll
        for (int ni = 0; ni < 8; ++ni) {
            float qv[4], kv[4];
#pragma unroll
            for (int t = 0; t < 4; ++t) {
                qv[t] = aQ[mi][ni][t] + qb[ni];
                kv[t] = aK[mi][ni][t] + kb[ni];
            }
#pragma unroll
            for (int t = 0; t < 4; ++t)
#pragma unroll
                for (int j = 0; j < 4; ++j) ps[t][j] += qv[t] * kv[j];
        }
        // butterfly over the 16 col-lanes (bits 0..3 of lane)
#pragma unroll
        for (int t = 0; t < 4; ++t)
#pragma unroll
            for (int j = 0; j < 4; ++j) {
                ps[t][j] += __shfl_xor(ps[t][j], 1);
                ps[t][j] += __shfl_xor(ps[t][j], 2);
                ps[t][j] += __shfl_xor(ps[t][j], 4);
                ps[t][j] += __shfl_xor(ps[t][j], 8);
            }

        const float scale = 0.08838834764831845f;   // 1/sqrt(128)
        float qj[4];
#pragma unroll
        for (int j = 0; j < 4; ++j) qj[j] = qual[bbat * 4 + j] * scale;

        float wsum[4] = {0.f, 0.f, 0.f, 0.f};
#pragma unroll
        for (int t = 0; t < 4; ++t) {
            float sm[4]; float mx = -1e30f;
#pragma unroll
            for (int j = 0; j < 4; ++j) { sm[j] = ps[t][j] * qj[j]; mx = fmaxf(mx, sm[j]); }
            float ex[4]; float se = 0.f;
#pragma unroll
            for (int j = 0; j < 4; ++j) { ex[j] = __expf(sm[j] - mx); se += ex[j]; }
            const float inv = 0.25f / se;
#pragma unroll
            for (int j = 0; j < 4; ++j) wsum[j] += ex[j] * inv;
        }

        // ctx[bbat][col] = sum_j wsum[j] * Vproj[4b+j][col] + bv[col]
        // (sum_j wsum[j] == 1, so bias coefficient is exactly 1)
#pragma unroll
        for (int ni = 0; ni < 8; ++ni) {
            const int col = n0 + ni * 16 + lcol;
            float r = wsum[0] * aV[mi][ni][0] + wsum[1] * aV[mi][ni][1]
                    + wsum[2] * aV[mi][ni][2] + wsum[3] * aV[mi][ni][3] + vb[ni];
            ctx[(size_t)bbat * DD + col] = f2b(r);
        }
    }
}

// ---------------------------------------------------------------------------
// o_gemm: Y (f32) = ctx @ Wo^T + bo.  Pure m97 structure, contiguous A.
// ---------------------------------------------------------------------------
__global__ __launch_bounds__(256) void o_gemm(
    const u16* __restrict__ A, const u16* __restrict__ W,
    const float* __restrict__ bia, float* __restrict__ Y)
{
    __shared__ __align__(16) u16 As[128 * 32];
    __shared__ __align__(16) u16 Bs[128 * 32];

    const int tid = threadIdx.x;
    const int m0 = blockIdx.x * 128;
    const int n0 = blockIdx.y * 128;

    const int rs = tid >> 2;
    const int ks = (tid & 3) * 8;
    const u16* srcA1 = A + (size_t)(m0 + rs) * DD + ks;
    const u16* srcA2 = srcA1 + (size_t)64 * DD;
    const u16* srcB1 = W + (size_t)(n0 + rs) * DD + ks;
    const u16* srcB2 = srcB1 + (size_t)64 * DD;

    const int wave = tid >> 6;
    char* ldsA1 = (char*)As + wave * 1024;
    char* ldsA2 = (char*)As + 4096 + wave * 1024;
    char* ldsB1 = (char*)Bs + wave * 1024;
    char* ldsB2 = (char*)Bs + 4096 + wave * 1024;

    const int lane = tid & 63;
    const int wm = (wave >> 1) * 64;
    const int wn = (wave & 1) * 64;
    const int lrow = lane & 15;
    const int lk = (lane >> 4) * 8;

    f32x4 acc[4][4] = {};

    for (int k0 = 0; k0 < DD; k0 += 32) {
        __syncthreads();
        load_lds16(srcA1, ldsA1);
        load_lds16(srcA2, ldsA2);
        load_lds16(srcB1, ldsB1);
        load_lds16(srcB2, ldsB2);
        srcA1 += 32; srcA2 += 32; srcB1 += 32; srcB2 += 32;
        __syncthreads();

        bf16x8 af[4], bfr[4];
#pragma unroll
        for (int i = 0; i < 4; ++i)
            af[i] = *(const bf16x8*)(As + (wm + i * 16 + lrow) * 32 + lk);
#pragma unroll
        for (int i = 0; i < 4; ++i)
            bfr[i] = *(const bf16x8*)(Bs + (wn + i * 16 + lrow) * 32 + lk);
#pragma unroll
        for (int mi = 0; mi < 4; ++mi)
#pragma unroll
            for (int ni = 0; ni < 4; ++ni)
                acc[mi][ni] = __builtin_amdgcn_mfma_f32_16x16x32_bf16(af[mi], bfr[ni], acc[mi][ni], 0, 0, 0);
    }

#pragma unroll
    for (int mi = 0; mi < 4; ++mi) {
#pragma unroll
        for (int r = 0; r < 4; ++r) {
            const int grow = m0 + wm + mi * 16 + (lane >> 4) * 4 + r;
#pragma unroll
            for (int ni = 0; ni < 4; ++ni) {
                const int gcol = n0 + wn + ni * 16 + (lane & 15);
                Y[(size_t)grow * DD + gcol] = acc[mi][ni][r] + bia[gcol];
            }
        }
    }
}

// ---------------------------------------------------------------------------
// ln_kernel: residual mean + LayerNorm.  One block per row; all f32 I/O.
// ---------------------------------------------------------------------------
__global__ __launch_bounds__(256) void ln_kernel(
    const float* __restrict__ Y,
    const float* __restrict__ e0, const float* __restrict__ e1,
    const float* __restrict__ e2, const float* __restrict__ e3,
    const float* __restrict__ gamma, const float* __restrict__ beta,
    float* __restrict__ out)
{
    const int r = blockIdx.x;
    const int tid = threadIdx.x;
    const int c = tid * 8;
    const size_t base = (size_t)r * DD + c;

    float v[8];
    {
        float4 y0 = *(const float4*)(Y + base);
        float4 y1 = *(const float4*)(Y + base + 4);
        float a[8] = {0, 0, 0, 0, 0, 0, 0, 0};
        const float* eps[4] = {e0, e1, e2, e3};
#pragma unroll
        for (int qq = 0; qq < 4; ++qq) {
            float4 p0 = *(const float4*)(eps[qq] + base);
            float4 p1 = *(const float4*)(eps[qq] + base + 4);
            a[0] += p0.x; a[1] += p0.y; a[2] += p0.z; a[3] += p0.w;
            a[4] += p1.x; a[5] += p1.y; a[6] += p1.z; a[7] += p1.w;
        }
        float yv[8] = {y0.x, y0.y, y0.z, y0.w, y1.x, y1.y, y1.z, y1.w};
#pragma unroll
        for (int i = 0; i < 8; ++i) v[i] = yv[i] + 0.25f * a[i];
    }

    float s = 0.f, sq = 0.f;
#pragma unroll
    for (int i = 0; i < 8; ++i) { s += v[i]; sq += v[i] * v[i]; }
#pragma unroll
    for (int off = 32; off >= 1; off >>= 1) {
        s += __shfl_xor(s, off);
        sq += __shfl_xor(sq, off);
    }
    __shared__ float sh[8];
    const int lane = tid & 63, wv = tid >> 6;
    if (lane == 0) { sh[wv] = s; sh[4 + wv] = sq; }
    __syncthreads();
    s = sh[0] + sh[1] + sh[2] + sh[3];
    sq = sh[4] + sh[5] + sh[6] + sh[7];

    const float invD = 1.0f / 2048.0f;
    const float mu = s * invD;
    const float rs = rsqrtf(sq * invD - mu * mu + 1e-5f);

    float4 g0 = *(const float4*)(gamma + c);
    float4 g1 = *(const float4*)(gamma + c + 4);
    float4 b0 = *(const float4*)(beta + c);
    float4 b1 = *(const float4*)(beta + c + 4);
    float gg[8] = {g0.x, g0.y, g0.z, g0.w, g1.x, g1.y, g1.z, g1.w};
    float bb[8] = {b0.x, b0.y, b0.z, b0.w, b1.x, b1.y, b1.z, b1.w};

    float o[8];
#pragma unroll
    for (int i = 0; i < 8; ++i) o[i] = (v[i] - mu) * rs * gg[i] + bb[i];
    *(float4*)(out + base)     = make_float4(o[0], o[1], o[2], o[3]);
    *(float4*)(out + base + 4) = make_float4(o[4], o[5], o[6], o[7]);
}

// ---------------------------------------------------------------------------
extern "C" void kernel_launch(void* const* d_in, const int* in_sizes, int n_in,
                              void* d_out, int out_size, void* d_ws, size_t ws_size,
                              hipStream_t stream)
{
    const float* e0   = (const float*)d_in[0];
    const float* e1   = (const float*)d_in[1];
    const float* e2   = (const float*)d_in[2];
    const float* e3   = (const float*)d_in[3];
    const float* qual = (const float*)d_in[4];
    const float* Wq   = (const float*)d_in[5];
    const float* bq   = (const float*)d_in[6];
    const float* Wk   = (const float*)d_in[7];
    const float* bk   = (const float*)d_in[8];
    const float* Wv   = (const float*)d_in[9];
    const float* bv   = (const float*)d_in[10];
    const float* Wo   = (const float*)d_in[11];
    const float* bo   = (const float*)d_in[12];
    const float* gm   = (const float*)d_in[13];
    const float* bt   = (const float*)d_in[14];

    const size_t WD = (size_t)DD * DD;            // 4,194,304
    const size_t MQ = (size_t)BB * NTT * DD;      // 33,554,432
    const size_t ED = (size_t)BB * DD;            // 8,388,608

    // workspace (u16 units): Ebf 67.1MB + W4 33.6MB + ctx 16.8MB + Y 33.6MB
    // = 151 MB total (well under the 218 MB proven budget).
    u16* Ebf = (u16*)d_ws;                        // MQ
    u16* W4  = Ebf + MQ;                          // 4*WD  (q,k,v,o)
    u16* ctx = W4 + 4 * WD;                       // ED
    float* Y = (float*)(ctx + ED);                // ED floats

    // stage 0: all conversions in one dispatch
    cvt_all<<<dim3(24576), 256, 0, stream>>>(e0, e1, e2, e3, Wq, Wk, Wv, Wo,
                                             Ebf, W4);

    // stage 1: fused QKV projection + attention -> ctx (B x D)
    qkv_attn<<<dim3(16, 128), 256, 0, stream>>>(Ebf, W4, W4 + WD, W4 + 2 * WD,
                                                bq, bk, bv, qual, ctx);

    // stage 2: O projection -> Y f32
    o_gemm<<<dim3(32, 16), 256, 0, stream>>>(ctx, W4 + 3 * WD, bo, Y);

    // stage 3: residual mean + LayerNorm
    ln_kernel<<<dim3(4096), 256, 0, stream>>>(Y, e0, e1, e2, e3, gm, bt,
                                              (float*)d_out);
}